// Round 1
// baseline (134.238 us; speedup 1.0000x reference)
//
#include <hip/hip_runtime.h>
#include <math.h>

// Problem constants (match reference)
constexpr int BATCH = 256;
constexpr int S     = 64;
constexpr int D     = 64;
constexpr int F     = 10;
constexpr int NPAIR = S * (S - 1) / 2;  // 2016

// LDS layout (float offsets). Total 15888 floats = 63552 B < 64 KB.
constexpr int OFF_U    = 0;             // [64][68]  U' = emb@W1a + b1   (stride 68: b128-aligned, banks balanced)
constexpr int OFF_V    = 4352;          // [64][68]  V  = emb@W1b
constexpr int OFF_EMBT = 8704;          // [64][64]  embT[k][s]  (dead after cluster phase)
constexpr int OFF_FHT  = 8704;          // [64][65]  relu freq-hidden, transposed [d][s] (unioned over EMBT)
constexpr int OFF_PART = 12864;         // [16][64]  phase-B partials
constexpr int OFF_HSUM = 13888;         // [64]
constexpr int OFF_CS   = 13952;         // [16]      combo_sum
constexpr int OFF_FF   = 13968;         // [64][10]  freq_feat
constexpr int OFF_DIST = 14608;         // [64][10]  cluster distances
constexpr int OFF_CF   = 15248;         // [64][10]  cluster softmax
constexpr int LDS_FLOATS = 15888;

__device__ __forceinline__ void racc(float4& a, const float4 u, const float4 v) {
  a.x += fmaxf(u.x + v.x, 0.f);
  a.y += fmaxf(u.y + v.y, 0.f);
  a.z += fmaxf(u.z + v.z, 0.f);
  a.w += fmaxf(u.w + v.w, 0.f);
}

__global__ __launch_bounds__(256)
void cat_enc_kernel(const int*   __restrict__ ids,
                    const float* __restrict__ emb_table,
                    const float* __restrict__ comb_w1,
                    const float* __restrict__ comb_b1,
                    const float* __restrict__ comb_w2,
                    const float* __restrict__ comb_b2,
                    const float* __restrict__ freq_w1,
                    const float* __restrict__ freq_b1,
                    const float* __restrict__ freq_w2,
                    const float* __restrict__ freq_b2,
                    const float* __restrict__ centers,
                    const float* __restrict__ cat_freq,
                    const float* __restrict__ total_samples,
                    float*       __restrict__ out)
{
  __shared__ __align__(16) float lds[LDS_FLOATS];
  const int tid   = threadIdx.x;
  const int b     = blockIdx.x;
  const int bBase = b * S;

  // ---------- gather: embT[k][s] = emb_table[ids[b][s]][k] ----------
  {
    const int s  = tid & 63;
    const int kq = tid >> 6;                 // 0..3 -> k chunk of 16
    const int id = ids[bBase + s];
    const float* row = emb_table + (size_t)id * D + kq * 16;
    float4 r0 = ((const float4*)row)[0];
    float4 r1 = ((const float4*)row)[1];
    float4 r2 = ((const float4*)row)[2];
    float4 r3 = ((const float4*)row)[3];
    float vv[16] = { r0.x, r0.y, r0.z, r0.w, r1.x, r1.y, r1.z, r1.w,
                     r2.x, r2.y, r2.z, r2.w, r3.x, r3.y, r3.z, r3.w };
#pragma unroll
    for (int m = 0; m < 16; ++m)
      lds[OFF_EMBT + (kq * 16 + m) * 64 + s] = vv[m];   // lanes stride-1: conflict-free
  }
  __syncthreads();

  // ---------- cluster distances: dist[s][c] = sqrt(sum_k (e-c)^2) ----------
  {
    const int s  = tid & 63;
    const int cg = __builtin_amdgcn_readfirstlane((int)(tid >> 6));  // 0..3, wave-uniform
    const int c0 = cg, c1 = cg + 4, c2 = cg + 8;                     // c2 valid only cg<2
    float d2a = 0.f, d2b = 0.f, d2c = 0.f;
#pragma unroll 4
    for (int k = 0; k < D; ++k) {
      float e  = lds[OFF_EMBT + k * 64 + s];
      float ca = centers[c0 * D + k];          // uniform -> s_load
      float cb = centers[c1 * D + k];
      float ta = e - ca, tb = e - cb;
      d2a = fmaf(ta, ta, d2a);
      d2b = fmaf(tb, tb, d2b);
      if (cg < 2) { float cc = centers[c2 * D + k]; float tc = e - cc; d2c = fmaf(tc, tc, d2c); }
    }
    lds[OFF_DIST + s * 10 + c0] = sqrtf(d2a);
    lds[OFF_DIST + s * 10 + c1] = sqrtf(d2b);
    if (cg < 2) lds[OFF_DIST + s * 10 + c2] = sqrtf(d2c);
  }
  __syncthreads();   // also guards FHT writes aliasing EMBT reads

  // ---------- phase A: U' = emb@W1a+b1 ; V = emb@W1b ; FH = relu(emb@FW1 + fq*fw1[D] + fb1) ----------
  {
    const int d  = tid & 63;
    const int w  = __builtin_amdgcn_readfirstlane((int)(tid >> 6));  // wave id, uniform
    const int s0 = w * 16;
    const float invT = 1.0f / total_samples[0];

    int idv[16];
#pragma unroll
    for (int si = 0; si < 16; ++si) idv[si] = ids[bBase + s0 + si];  // uniform -> SGPRs

    float accU[16], accV[16], accF[16];
    const float b1d  = comb_b1[d];
    const float fb1d = freq_b1[d];
    const float fw1L = freq_w1[D * D + d];   // freq_w1 row D (the frequency input column)
#pragma unroll
    for (int si = 0; si < 16; ++si) {
      accU[si] = b1d;
      accV[si] = 0.f;
      float fq = cat_freq[idv[si]] * invT;   // uniform
      accF[si] = fmaf(fq, fw1L, fb1d);
    }

#pragma unroll 4
    for (int k = 0; k < D; ++k) {
      float wu = comb_w1[k * D + d];         // coalesced vector loads, lanes over d
      float wv = comb_w1[(D + k) * D + d];
      float wf = freq_w1[k * D + d];
#pragma unroll
      for (int si = 0; si < 16; ++si) {
        float e = emb_table[(size_t)idv[si] * D + k];  // wave-uniform -> s_load
        accU[si] = fmaf(e, wu, accU[si]);
        accV[si] = fmaf(e, wv, accV[si]);
        accF[si] = fmaf(e, wf, accF[si]);
      }
    }

#pragma unroll
    for (int si = 0; si < 16; ++si) {
      lds[OFF_U + (s0 + si) * 68 + d]   = accU[si];              // lanes stride-1: free
      lds[OFF_V + (s0 + si) * 68 + d]   = accV[si];
      lds[OFF_FHT + d * 65 + (s0 + si)] = fmaxf(accF[si], 0.f);  // stride 65: 2-way, free
    }
  }
  __syncthreads();

  // ---------- phase B: Hsum partials = sum_{i<j} relu(U'[i]+V[j]) ----------
  {
    const int dg = tid & 15;
    const int g  = tid >> 4;           // 0..15; uniform per 16-lane group
    const int d4 = dg * 4;
    // balanced i-set: exactly 126 pairs per thread for every g
    const int i0 = 2 * g, i1 = 2 * g + 1, i2 = 62 - 2 * g, i3 = 63 - 2 * g;
    const float* Ub = &lds[OFF_U];
    const float* Vb = &lds[OFF_V];
    const float4 u0 = *(const float4*)(Ub + i0 * 68 + d4);
    const float4 u1 = *(const float4*)(Ub + i1 * 68 + d4);
    const float4 u2 = *(const float4*)(Ub + i2 * 68 + d4);
    const float4 u3 = *(const float4*)(Ub + i3 * 68 + d4);
    float4 acc = make_float4(0.f, 0.f, 0.f, 0.f);
    {                                   // j = i1: only i0 < j
      float4 v = *(const float4*)(Vb + i1 * 68 + d4);
      racc(acc, u0, v);
    }
#pragma unroll 4
    for (int j = i1 + 1; j <= i2; ++j) {  // i0,i1 active
      float4 v = *(const float4*)(Vb + j * 68 + d4);
      racc(acc, u0, v); racc(acc, u1, v);
    }
    {                                   // j = i3: i0,i1,i2 active
      float4 v = *(const float4*)(Vb + i3 * 68 + d4);
      racc(acc, u0, v); racc(acc, u1, v); racc(acc, u2, v);
    }
#pragma unroll 4
    for (int j = i3 + 1; j < 64; ++j) { // all four active
      float4 v = *(const float4*)(Vb + j * 68 + d4);
      racc(acc, u0, v); racc(acc, u1, v); racc(acc, u2, v); racc(acc, u3, v);
    }
    *(float4*)(&lds[OFF_PART + g * 64 + d4]) = acc;
  }

  // ---------- phase C: freq_feat[s][f] = FH[s]@fw2 + fb2  (reads FHT, pre-barrier data) ----------
  {
    const int s  = tid & 63;
    const int fg = __builtin_amdgcn_readfirstlane((int)(tid >> 6));  // f in {fg, fg+4, fg+8(<10)}
    float f0 = 0.f, f1 = 0.f, f2 = 0.f;
#pragma unroll 4
    for (int dd = 0; dd < D; ++dd) {
      float fh = lds[OFF_FHT + dd * 65 + s];
      f0 = fmaf(fh, freq_w2[dd * 10 + fg],     f0);    // uniform -> s_load
      f1 = fmaf(fh, freq_w2[dd * 10 + fg + 4], f1);
      if (fg < 2) f2 = fmaf(fh, freq_w2[dd * 10 + fg + 8], f2);
    }
    lds[OFF_FF + s * 10 + fg]     = f0 + freq_b2[fg];
    lds[OFF_FF + s * 10 + fg + 4] = f1 + freq_b2[fg + 4];
    if (fg < 2) lds[OFF_FF + s * 10 + fg + 8] = f2 + freq_b2[fg + 8];
  }

  // ---------- softmax over -dist (reads DIST, pre-barrier data) ----------
  if (tid < 64) {
    float dv[10]; float dmin = 1e30f;
#pragma unroll
    for (int c = 0; c < 10; ++c) { dv[c] = lds[OFF_DIST + tid * 10 + c]; dmin = fminf(dmin, dv[c]); }
    float p[10]; float sum = 0.f;
#pragma unroll
    for (int c = 0; c < 10; ++c) { p[c] = expf(dmin - dv[c]); sum += p[c]; }
    float r = 1.0f / sum;
#pragma unroll
    for (int c = 0; c < 10; ++c) lds[OFF_CF + tid * 10 + c] = p[c] * r;
  }
  __syncthreads();

  // ---------- Hsum reduce ----------
  if (tid < 64) {
    float h = 0.f;
#pragma unroll
    for (int g = 0; g < 16; ++g) h += lds[OFF_PART + g * 64 + tid];
    lds[OFF_HSUM + tid] = h;
  }
  __syncthreads();

  // ---------- combo_sum[f] = Hsum@W2 + P*b2 ----------
  if (tid < F) {
    float cs = comb_b2[tid] * (float)NPAIR;
#pragma unroll 4
    for (int dd = 0; dd < D; ++dd)
      cs = fmaf(lds[OFF_HSUM + dd], comb_w2[dd * 10 + tid], cs);
    lds[OFF_CS + tid] = cs;
  }
  __syncthreads();

  // ---------- epilogue: out = (freq_feat + combo_sum + cluster_feat) / (P+2) ----------
  {
    const float inv = 1.0f / (float)(NPAIR + 2);
    for (int idx = tid; idx < S * F; idx += 256) {
      int f = idx % 10;
      float val = (lds[OFF_FF + idx] + lds[OFF_CS + f] + lds[OFF_CF + idx]) * inv;
      out[b * S * F + idx] = val;
    }
  }
}

extern "C" void kernel_launch(void* const* d_in, const int* in_sizes, int n_in,
                              void* d_out, int out_size, void* d_ws, size_t ws_size,
                              hipStream_t stream) {
  (void)in_sizes; (void)n_in; (void)d_ws; (void)ws_size; (void)out_size;
  const int*   ids        = (const int*)  d_in[0];
  const float* emb_table  = (const float*)d_in[1];
  const float* comb_w1    = (const float*)d_in[2];
  const float* comb_b1    = (const float*)d_in[3];
  const float* comb_w2    = (const float*)d_in[4];
  const float* comb_b2    = (const float*)d_in[5];
  const float* freq_w1    = (const float*)d_in[6];
  const float* freq_b1    = (const float*)d_in[7];
  const float* freq_w2    = (const float*)d_in[8];
  const float* freq_b2    = (const float*)d_in[9];
  const float* centers    = (const float*)d_in[10];
  const float* cat_freq   = (const float*)d_in[11];
  const float* total_samp = (const float*)d_in[12];
  float* out = (float*)d_out;

  hipLaunchKernelGGL(cat_enc_kernel, dim3(BATCH), dim3(256), 0, stream,
                     ids, emb_table, comb_w1, comb_b1, comb_w2, comb_b2,
                     freq_w1, freq_b1, freq_w2, freq_b2, centers, cat_freq,
                     total_samp, out);
}

// Round 2
// 107.803 us; speedup vs baseline: 1.2452x; 1.2452x over previous
//
#include <hip/hip_runtime.h>
#include <math.h>

// ---------------------------------------------------------------------------
// CategoricalAwareTabularEncoder — design 2 (f16-packed, 1024 thr/block)
//
// Key algebra: pair-MLP layer-1 factorizes: pairs(i,j)@W1 = emb_i@W1a + emb_j@W1b.
// So: U = emb@W1a + b1, V = emb@W1b  (per token), then
//     Hsum[d] = sum_{i<j} relu(U_i[d] + V_j[d]),  combo_sum = Hsum@W2 + P*b2.
// Work drops from ~9.1 GFLOP to ~0.5 GFLOP for the whole batch.
// ---------------------------------------------------------------------------

typedef _Float16 h2 __attribute__((ext_vector_type(2)));
typedef _Float16 h4 __attribute__((ext_vector_type(4)));

constexpr int BATCH = 256;
constexpr int S = 64, D = 64, F = 10;
constexpr int NPAIR = S * (S - 1) / 2;  // 2016

// LDS map in 4-byte units (total 16000 = 64000 B)
// Weights f16x2, two b32 planes per matrix (conflict-free lane=d reads):
//   WU lo @0 hi @1024 | WV lo @2048 hi @3072 | WF lo @4096 hi @5120, idx k4*64+d
//   After phase A this region is dead -> aliased:
//     PART f32 [32 g][64 d] @0..2047 | FF f32 [64][10] @2048..2687
//     HSUM f32 @2688..2751 | CS f32 @2752..2761
constexpr int EMBS = 6144;   // [s][k2] f16x2 (2048)
constexpr int U2B  = 8192;   // [s][d2] f16x2 (2048)
constexpr int V2B  = 10240;  // [s][d2] f16x2 (2048)
constexpr int FHT  = 12288;  // [s][d2] f16x2, row stride 33 (2112); aliases EMBT
constexpr int EMBT = 12288;  // [k2][s] f16x2 (2048), dead after cluster phase
constexpr int CF_F = 14400;  // f32 [64][10] cluster softmax (640)
constexpr int DI_F = 15040;  // f32 [64][10] distances (640)
constexpr int W2P  = 15680;  // [d2*10+f] f16x2 packed freq_w2 (320)
constexpr int PART_F = 0;
constexpr int FF_F   = 2048;
constexpr int HS_F   = 2688;
constexpr int CS_F   = 2752;

__device__ __forceinline__ h2 pk2(float a, float b) {
#if __has_builtin(__builtin_amdgcn_cvt_pkrtz)
  auto t = __builtin_amdgcn_cvt_pkrtz(a, b);
  return __builtin_bit_cast(h2, t);
#else
  h2 r; r.x = (_Float16)a; r.y = (_Float16)b; return r;
#endif
}

__device__ __forceinline__ float fdot2f(h2 a, h2 b, float c) {
#if __has_builtin(__builtin_amdgcn_fdot2)
  typedef __fp16 q2 __attribute__((ext_vector_type(2)));
  return __builtin_amdgcn_fdot2(__builtin_bit_cast(q2, a),
                                __builtin_bit_cast(q2, b), c, false);
#else
  return c + (float)a.x * (float)b.x + (float)a.y * (float)b.y;
#endif
}

__device__ __forceinline__ h2 hmax2z(h2 a) {  // elementwise max(a, 0)
#if __has_builtin(__builtin_elementwise_max)
  h2 z = {(_Float16)0, (_Float16)0};
  return __builtin_elementwise_max(a, z);
#else
  h2 r;
  r.x = a.x > (_Float16)0 ? a.x : (_Float16)0;
  r.y = a.y > (_Float16)0 ? a.y : (_Float16)0;
  return r;
#endif
}

// value of lane (l+1) for even lanes l, via quad_perm [1,1,3,3]
__device__ __forceinline__ float lane_up1(float v) {
#if __has_builtin(__builtin_amdgcn_update_dpp)
  int r = __builtin_amdgcn_update_dpp(0, __float_as_int(v), 0xF5, 0xF, 0xF, false);
  return __int_as_float(r);
#else
  return __shfl_down(v, 1, 64);
#endif
}

__global__ __launch_bounds__(1024, 4)
void cat_enc_kernel(const int*   __restrict__ ids,
                    const float* __restrict__ emb_table,
                    const float* __restrict__ comb_w1,
                    const float* __restrict__ comb_b1,
                    const float* __restrict__ comb_w2,
                    const float* __restrict__ comb_b2,
                    const float* __restrict__ freq_w1,
                    const float* __restrict__ freq_b1,
                    const float* __restrict__ freq_w2,
                    const float* __restrict__ freq_b2,
                    const float* __restrict__ centers,
                    const float* __restrict__ cat_freq,
                    const float* __restrict__ total_samples,
                    float*       __restrict__ out)
{
  __shared__ __align__(16) unsigned int ldsu[16000];
  h2*    ldsH = (h2*)ldsu;
  float* ldsf = (float*)ldsu;
  const int tid = threadIdx.x;
  const int b = blockIdx.x, bBase = b * S;

  // ---------------- stage: pack weights + gather emb (both layouts) ---------
  {
    for (int task = tid; task < 3072; task += 1024) {
      int mat = task >> 10, r = task & 1023, k4 = r >> 6, d = r & 63;
      const float* src = (mat == 0) ? (comb_w1 + (k4 * 4) * D + d)
                       : (mat == 1) ? (comb_w1 + (D + k4 * 4) * D + d)
                                    : (freq_w1 + (k4 * 4) * D + d);
      float w0 = src[0], w1 = src[D], w2v = src[2 * D], w3 = src[3 * D];
      ldsH[mat * 2048 + k4 * 64 + d]        = pk2(w0, w1);
      ldsH[mat * 2048 + 1024 + k4 * 64 + d] = pk2(w2v, w3);
    }
    int s = tid >> 4, q = tid & 15;
    int id = ids[bBase + s];
    float4 e4 = *(const float4*)(emb_table + (size_t)id * D + q * 4);
    h2 p0 = pk2(e4.x, e4.y), p1 = pk2(e4.z, e4.w);
    ldsH[EMBS + s * 32 + q * 2]     = p0;
    ldsH[EMBS + s * 32 + q * 2 + 1] = p1;
    ldsH[EMBT + (q * 2) * 64 + s]     = p0;
    ldsH[EMBT + (q * 2 + 1) * 64 + s] = p1;
    if (tid < 320) {
      int d2 = tid / 10, f = tid - d2 * 10;
      ldsH[W2P + tid] = pk2(freq_w2[(2 * d2) * F + f], freq_w2[(2 * d2 + 1) * F + f]);
    }
  }
  __syncthreads();

  // ---------------- cluster distances: wave c (0..9) does center c ----------
  {
    int wv = __builtin_amdgcn_readfirstlane((int)(tid >> 6));
    int lane = tid & 63;
    if (wv < 10) {
      const float* crow = centers + wv * D;  // uniform -> s_load
      float acc = 0.f;
#pragma unroll 8
      for (int k2 = 0; k2 < 32; ++k2) {
        h2 e2 = ldsH[EMBT + k2 * 64 + lane];        // stride-1 lanes, conflict-free
        float t0 = (float)e2.x - crow[2 * k2];
        float t1 = (float)e2.y - crow[2 * k2 + 1];
        acc = fmaf(t0, t0, fmaf(t1, t1, acc));
      }
      ldsf[DI_F + lane * 10 + wv] = sqrtf(acc);
    }
  }
  __syncthreads();  // FHT (phase A) overwrites EMBT

  // ---------------- phase A: U,V,FH for 4 tokens per wave, lane = d ---------
  {
    const int d  = tid & 63;
    const int wv = __builtin_amdgcn_readfirstlane((int)(tid >> 6));
    const int s0 = wv * 4;
    const float invT = 1.0f / total_samples[0];
    int idv[4];
#pragma unroll
    for (int si = 0; si < 4; ++si)
      idv[si] = __builtin_amdgcn_readfirstlane(ids[bBase + s0 + si]);
    const float b1d = comb_b1[d], fb1d = freq_b1[d], fw1L = freq_w1[D * D + d];
    float aU[4], aV[4], aF[4];
#pragma unroll
    for (int si = 0; si < 4; ++si) {
      aU[si] = b1d; aV[si] = 0.f;
      aF[si] = fmaf(cat_freq[idv[si]] * invT, fw1L, fb1d);
    }
#pragma unroll 4
    for (int k4 = 0; k4 < 16; ++k4) {
      h2 wul = ldsH[k4 * 64 + d],        wuh = ldsH[1024 + k4 * 64 + d];
      h2 wvl = ldsH[2048 + k4 * 64 + d], wvh = ldsH[3072 + k4 * 64 + d];
      h2 wfl = ldsH[4096 + k4 * 64 + d], wfh = ldsH[5120 + k4 * 64 + d];
#pragma unroll
      for (int si = 0; si < 4; ++si) {
        h4 e = *(const h4*)&ldsH[EMBS + (s0 + si) * 32 + k4 * 2];  // b64 broadcast
        h2 el = e.lo, eh = e.hi;
        aU[si] = fdot2f(el, wul, aU[si]); aU[si] = fdot2f(eh, wuh, aU[si]);
        aV[si] = fdot2f(el, wvl, aV[si]); aV[si] = fdot2f(eh, wvh, aV[si]);
        aF[si] = fdot2f(el, wfl, aF[si]); aF[si] = fdot2f(eh, wfh, aF[si]);
      }
    }
    // pack (d, d+1) pairs across even/odd lanes, store f16x2
    const bool evenl = ((d & 1) == 0);
    const int d2 = d >> 1;
#pragma unroll
    for (int si = 0; si < 4; ++si) {
      float un = lane_up1(aU[si]);
      float vn = lane_up1(aV[si]);
      float fh = fmaxf(aF[si], 0.f);
      float fn = lane_up1(fh);
      if (evenl) {
        int srow = s0 + si;
        ldsH[U2B + srow * 32 + d2] = pk2(aU[si], un);
        ldsH[V2B + srow * 32 + d2] = pk2(aV[si], vn);
        ldsH[FHT + srow * 33 + d2] = pk2(fh, fn);
      }
    }
  }
  __syncthreads();

  // ------- phase C (waves 0..9: freq_feat) + softmax (wave 10) --------------
  {
    if (tid < 640) {
      int s = tid & 63;
      int f = __builtin_amdgcn_readfirstlane((int)(tid >> 6));  // wave = f
      float acc = freq_b2[f];
#pragma unroll 8
      for (int d2 = 0; d2 < 32; ++d2)
        acc = fdot2f(ldsH[FHT + s * 33 + d2], ldsH[W2P + d2 * 10 + f], acc);
      ldsf[FF_F + s * 10 + f] = acc;
    } else if (tid < 704) {
      int s = tid - 640;
      float dv[10], dmin = 1e30f;
#pragma unroll
      for (int c = 0; c < 10; ++c) { dv[c] = ldsf[DI_F + s * 10 + c]; dmin = fminf(dmin, dv[c]); }
      float p[10], sum = 0.f;
#pragma unroll
      for (int c = 0; c < 10; ++c) { p[c] = expf(dmin - dv[c]); sum += p[c]; }
      float rs = 1.0f / sum;
#pragma unroll
      for (int c = 0; c < 10; ++c) ldsf[CF_F + s * 10 + c] = p[c] * rs;
    }
  }

  // ------- phase B: Hsum partials, group g owns rows {g, 63-g} --------------
  {
    const int dg = tid & 31, g = tid >> 5;
    h2 u2a = ldsH[U2B + g * 32 + dg];
    h2 u2b = ldsH[U2B + (63 - g) * 32 + dg];
    h2 za = {(_Float16)0, (_Float16)0};
    h2 acca = za, accb = za;
    const int jsplit = 64 - g;
#pragma unroll 4
    for (int j = g + 1; j < 64; ++j) {
      h2 v2 = ldsH[V2B + j * 32 + dg];
      acca = acca + hmax2z(u2a + v2);
      if (j >= jsplit) accb = accb + hmax2z(u2b + v2);
    }
    h2 at = acca + accb;
    ldsf[PART_F + g * 64 + 2 * dg]     = (float)at.x;
    ldsf[PART_F + g * 64 + 2 * dg + 1] = (float)at.y;
  }
  __syncthreads();

  // ------- Hsum reduce (wave 0) ---------------------------------------------
  if (tid < 64) {
    float h = 0.f;
#pragma unroll
    for (int g = 0; g < 32; ++g) h += ldsf[PART_F + g * 64 + tid];
    ldsf[HS_F + tid] = h;
  }
  __syncthreads();

  // ------- combo_sum --------------------------------------------------------
  if (tid < 10) {
    float cs = comb_b2[tid] * (float)NPAIR;
#pragma unroll 8
    for (int dd = 0; dd < 64; ++dd)
      cs = fmaf(ldsf[HS_F + dd], comb_w2[dd * F + tid], cs);
    ldsf[CS_F + tid] = cs;
  }
  __syncthreads();

  // ------- epilogue ---------------------------------------------------------
  if (tid < 640) {
    int f = tid % 10;
    float val = (ldsf[FF_F + tid] + ldsf[CS_F + f] + ldsf[CF_F + tid])
              * (1.0f / (float)(NPAIR + 2));
    out[(size_t)b * 640 + tid] = val;
  }
}

extern "C" void kernel_launch(void* const* d_in, const int* in_sizes, int n_in,
                              void* d_out, int out_size, void* d_ws, size_t ws_size,
                              hipStream_t stream) {
  (void)in_sizes; (void)n_in; (void)d_ws; (void)ws_size; (void)out_size;
  const int*   ids        = (const int*)  d_in[0];
  const float* emb_table  = (const float*)d_in[1];
  const float* comb_w1    = (const float*)d_in[2];
  const float* comb_b1    = (const float*)d_in[3];
  const float* comb_w2    = (const float*)d_in[4];
  const float* comb_b2    = (const float*)d_in[5];
  const float* freq_w1    = (const float*)d_in[6];
  const float* freq_b1    = (const float*)d_in[7];
  const float* freq_w2    = (const float*)d_in[8];
  const float* freq_b2    = (const float*)d_in[9];
  const float* centers    = (const float*)d_in[10];
  const float* cat_freq   = (const float*)d_in[11];
  const float* total_samp = (const float*)d_in[12];
  float* out = (float*)d_out;

  hipLaunchKernelGGL(cat_enc_kernel, dim3(BATCH), dim3(1024), 0, stream,
                     ids, emb_table, comb_w1, comb_b1, comb_w2, comb_b2,
                     freq_w1, freq_b1, freq_w2, freq_b2, centers, cat_freq,
                     total_samp, out);
}